// Round 12
// baseline (337.893 us; speedup 1.0000x reference)
//
#include <hip/hip_runtime.h>
#include <hip/hip_bf16.h>
#include <math.h>

// Problem constants (fixed by the reference)
constexpr int T_LEN = 2048;
constexpr int B_SZ  = 2;
constexpr int D_DIM = 768;
constexpr int H_NUM = 8;
constexpr int HD    = 96;        // D/H
constexpr int FFN   = 3072;
constexpr float EPS = 1e-5f;
constexpr int TB    = T_LEN * B_SZ;   // 4096 rows
constexpr int QKV_LD = 3 * D_DIM;     // 2304
constexpr int NSPLIT = 4;             // attention split-K factor
constexpr int CHUNK  = T_LEN / NSPLIT;   // 512 keys per block
// (1/sqrt(96)) * log2(e): softmax exp done as exp2 with one fused constant
constexpr float SC_LOG2E = 0.14724444458547f;

typedef __attribute__((ext_vector_type(8)))  short short8;
typedef __attribute__((ext_vector_type(4)))  short short4v;
typedef __attribute__((ext_vector_type(4)))  float f32x4;
typedef __attribute__((ext_vector_type(16))) float f32x16;

__device__ __forceinline__ short f2bf(float f) {
    union { float f; unsigned u; } v; v.f = f;
    return (short)((v.u + 0x7FFFu + ((v.u >> 16) & 1u)) >> 16);   // RNE
}
__device__ __forceinline__ float bf2f(short s) {
    union { unsigned u; float f; } v;
    v.u = ((unsigned)(unsigned short)s) << 16;
    return v.f;
}

// async global->LDS, 16B per lane; LDS dst = wave-uniform base + lane*16
__device__ __forceinline__ void async_ld16(const short* g, short* l) {
    __builtin_amdgcn_global_load_lds(
        (const __attribute__((address_space(1))) unsigned int*)g,
        (__attribute__((address_space(3))) unsigned int*)l, 16, 0, 0);
}

// ---------------------------------------------------------------------------
// Prep: fused fp32 -> bf16 conversion over 7 segments (x + 6 weight blobs)
// ---------------------------------------------------------------------------
struct CvtArgs {
    const float* src[7];
    short*       dst[7];
    int          end4[7];   // cumulative segment ends, in float4 units
};

__global__ __launch_bounds__(256)
void cvt_all(CvtArgs a, int total4) {
    const int i = blockIdx.x * 256 + threadIdx.x;
    if (i >= total4) return;
    int s = 0;
    while (i >= a.end4[s]) ++s;
    const int base = s ? a.end4[s - 1] : 0;
    const int j = i - base;
    const float4 v = ((const float4*)a.src[s])[j];
    short4v o;
    o[0] = f2bf(v.x); o[1] = f2bf(v.y); o[2] = f2bf(v.z); o[3] = f2bf(v.w);
    *(short4v*)(a.dst[s] + (size_t)j * 4) = o;
}

__global__ __launch_bounds__(256)
void concat_bias(const float* __restrict__ bq, const float* __restrict__ bk,
                 const float* __restrict__ bv, float* __restrict__ dst) {
    const int i = blockIdx.x * 256 + threadIdx.x;
    if (i >= QKV_LD) return;
    dst[i] = (i < 768) ? bq[i] : (i < 1536 ? bk[i - 768] : bv[i - 1536]);
}

// ---------------------------------------------------------------------------
// bf16 MFMA GEMM: C[M,N] = A[M,K] @ W[N,K]^T + bias[N]  (optional ReLU)
// m97-style: 128(M) x BN tile, BK=32, 256 threads = 4 waves (unchanged).
// ---------------------------------------------------------------------------
template <int BN, typename OutT, bool RELU>
__global__ __launch_bounds__(256)
void gemm_mfma(const short* __restrict__ A, const short* __restrict__ W,
               const float* __restrict__ bias, OutT* __restrict__ C,
               int M, int N, int K) {
    constexpr int NI = BN / 32;   // 16-col tiles per wave
    __shared__ __align__(16) short As[128 * 32];
    __shared__ __align__(16) short Bs[BN * 32];

    const int tid  = threadIdx.x;
    const int w    = tid >> 6;
    const int lane = tid & 63;
    const int l16  = lane & 15;
    const int q4   = lane >> 4;          // 0..3
    const int row0 = blockIdx.y * 128;
    const int col0 = blockIdx.x * BN;
    const int wm   = (w >> 1) * 64;      // wave m-offset in tile
    const int wn   = (w & 1) * (BN / 2); // wave n-offset in tile

    const short* gA0 = A + (size_t)(row0 + (tid >> 2)) * K + (tid & 3) * 8;
    const short* gA1 = gA0 + (size_t)64 * K;
    const short* gB0 = W + (size_t)(col0 + (tid >> 2)) * K + (tid & 3) * 8;
    const short* gB1 = gB0 + (size_t)64 * K;
    short* ldsA0 = As + w * 512;           // wave-uniform bases
    short* ldsA1 = As + 2048 + w * 512;
    short* ldsB0 = Bs + w * 512;
    short* ldsB1 = Bs + 2048 + w * 512;   // only used when BN==128

    f32x4 acc[4][NI];
#pragma unroll
    for (int mi = 0; mi < 4; ++mi)
#pragma unroll
        for (int ni = 0; ni < NI; ++ni)
#pragma unroll
            for (int r = 0; r < 4; ++r) acc[mi][ni][r] = 0.f;

    for (int k0 = 0; k0 < K; k0 += 32) {
        async_ld16(gA0, ldsA0);
        async_ld16(gA1, ldsA1);
        async_ld16(gB0, ldsB0);
        if constexpr (BN == 128) async_ld16(gB1, ldsB1);
        gA0 += 32; gA1 += 32; gB0 += 32;
        if constexpr (BN == 128) gB1 += 32;
        __syncthreads();   // drain glds

        short8 af[4], bfr[NI];
#pragma unroll
        for (int mi = 0; mi < 4; ++mi)
            af[mi] = *(const short8*)&As[(wm + mi * 16 + l16) * 32 + q4 * 8];
#pragma unroll
        for (int ni = 0; ni < NI; ++ni)
            bfr[ni] = *(const short8*)&Bs[(wn + ni * 16 + l16) * 32 + q4 * 8];
#pragma unroll
        for (int mi = 0; mi < 4; ++mi)
#pragma unroll
            for (int ni = 0; ni < NI; ++ni)
                acc[mi][ni] = __builtin_amdgcn_mfma_f32_16x16x32_bf16(
                    af[mi], bfr[ni], acc[mi][ni], 0, 0, 0);
        __syncthreads();
    }

    float bcol[NI];
#pragma unroll
    for (int ni = 0; ni < NI; ++ni) bcol[ni] = bias[col0 + wn + ni * 16 + l16];
#pragma unroll
    for (int mi = 0; mi < 4; ++mi) {
#pragma unroll
        for (int r = 0; r < 4; ++r) {
            const int row = row0 + wm + mi * 16 + q4 * 4 + r;
#pragma unroll
            for (int ni = 0; ni < NI; ++ni) {
                float v = acc[mi][ni][r] + bcol[ni];
                if (RELU) v = fmaxf(v, 0.f);
                const int col = col0 + wn + ni * 16 + l16;
                if constexpr (sizeof(OutT) == 2)
                    C[(size_t)row * N + col] = (OutT)f2bf(v);
                else
                    C[(size_t)row * N + col] = v;
            }
        }
    }
}

// ---------------------------------------------------------------------------
// MFMA bf16 flash attention v4r: split-K + no-max softmax (reverted from v5's
// register transpose — measured regression; the LDS P round-trip's many
// independent ds_write_b16 overlap better than a serialized shuffle chain).
// Grid (T/64, B*H, NSPLIT) = 2048 blocks. Each block: 64 q-rows x 512 keys,
// writes UNNORMALIZED partial O (bf16) + partial denominator l (f32);
// combine kernel sums and normalizes (exact: no-max softmax is linear).
// P = exp2(S * scale*log2e) — one fused constant, one v_mul + v_exp.
// ---------------------------------------------------------------------------
__global__ __launch_bounds__(128)
void attn_mfma(const short* __restrict__ qkv, short* __restrict__ Opart,
               float* __restrict__ lpart) {
    __shared__ short Ks[32][112];    // [key][d] bf16, padded
    __shared__ short Vt[128][44];    // [d][key] bf16, stride 44 (2-way banks)
    __shared__ short Pw[2][32][36];  // per-wave P, stride 36

    const int tid  = threadIdx.x;
    const int w    = tid >> 6;
    const int lane = tid & 63;
    const int l31  = lane & 31;
    const int h5   = lane >> 5;
    const int t0   = blockIdx.x * 64;
    const int bh   = blockIdx.y;
    const int split = blockIdx.z;
    const int b    = bh >> 3;
    const int h    = bh & 7;

    // Vt rows 96..127: row 96 = ones (denominator column), rest zero
    for (int i = tid; i < 32 * 44; i += 128) {
        const int rr = i / 44, cc = i % 44;
        Vt[96 + rr][cc] = (rr == 0 && cc < 32) ? (short)0x3F80 : (short)0;
    }

    // Q fragments straight from global bf16 (wave-private 32 q-rows)
    short8 qf[6];
    {
        const int qrow = t0 + w * 32 + l31;
        const short* qb = qkv + ((size_t)qrow * B_SZ + b) * QKV_LD + h * HD;
#pragma unroll
        for (int ks = 0; ks < 6; ++ks)
            qf[ks] = *(const short8*)&qb[ks * 16 + h5 * 8];
    }

    // --- staging assignments (wave-specialized), chunk-local keys ---
    const int k_row = lane >> 1;                  // wave 0: key row
    const int k_off = (lane & 1) * 48;            // wave 0: d-half
    const short* gK = qkv + ((size_t)(split * CHUNK + k_row) * B_SZ + b) * QKV_LD
                      + D_DIM + h * HD + k_off;
    const int dg = (lane & 7) * 12;               // wave 1: d-group
    const int kg = (lane >> 3) * 4;               // wave 1: key-group
    const short* gV = qkv + ((size_t)(split * CHUNK + kg) * B_SZ + b) * QKV_LD
                      + 2 * D_DIM + h * HD + dg;
    const size_t step  = (size_t)32 * B_SZ * QKV_LD;
    const size_t vrow  = (size_t)B_SZ * QKV_LD;   // one key row

    f32x16 oacc[4];
#pragma unroll
    for (int nt = 0; nt < 4; ++nt)
#pragma unroll
        for (int r = 0; r < 16; ++r) oacc[nt][r] = 0.f;

    // prefetch tile 0 (wave-specialized, registers)
    short8  kpf[6];
    short4v vpf[4][3];
    if (w == 0) {
#pragma unroll
        for (int j = 0; j < 6; ++j) kpf[j] = *(const short8*)(gK + j * 8);
    } else {
#pragma unroll
        for (int r = 0; r < 4; ++r)
#pragma unroll
            for (int c = 0; c < 3; ++c)
                vpf[r][c] = *(const short4v*)(gV + r * vrow + c * 4);
    }

    for (int it = 0; it < CHUNK / 32; ++it) {
        __syncthreads();   // previous tile fully consumed by both waves
        if (w == 0) {
#pragma unroll
            for (int j = 0; j < 6; ++j)
                *(short8*)&Ks[k_row][k_off + j * 8] = kpf[j];
        } else {
#pragma unroll
            for (int d = 0; d < 12; ++d) {
                short4v t;
                t[0] = vpf[0][d >> 2][d & 3];
                t[1] = vpf[1][d >> 2][d & 3];
                t[2] = vpf[2][d >> 2][d & 3];
                t[3] = vpf[3][d >> 2][d & 3];
                *(short4v*)&Vt[dg + d][kg] = t;
            }
        }
        __syncthreads();

        // prefetch next tile (latency hides behind this tile's compute)
        if (it + 1 < CHUNK / 32) {
            const size_t off = (size_t)(it + 1) * step;
            if (w == 0) {
#pragma unroll
                for (int j = 0; j < 6; ++j)
                    kpf[j] = *(const short8*)(gK + off + j * 8);
            } else {
#pragma unroll
                for (int r = 0; r < 4; ++r)
#pragma unroll
                    for (int c = 0; c < 3; ++c)
                        vpf[r][c] = *(const short4v*)(gV + off + r * vrow + c * 4);
            }
        }

        // S = Q.K^T
        f32x16 sa;
#pragma unroll
        for (int r = 0; r < 16; ++r) sa[r] = 0.f;
#pragma unroll
        for (int ks = 0; ks < 6; ++ks) {
            const short8 kf = *(const short8*)&Ks[l31][ks * 16 + h5 * 8];
            sa = __builtin_amdgcn_mfma_f32_32x32x16_bf16(qf[ks], kf, sa, 0, 0, 0);
        }

        // P = exp2(S * scale*log2e); C-layout -> LDS -> A-layout
#pragma unroll
        for (int r = 0; r < 16; ++r) {
            const float p = exp2f(sa[r] * SC_LOG2E);
            const int row = (r & 3) + 8 * (r >> 2) + 4 * h5;
            Pw[w][row][l31] = f2bf(p);
        }

        // O += P.V  (+ denominator column in n-tile 3)
#pragma unroll
        for (int ks2 = 0; ks2 < 2; ++ks2) {
            const short* pp = &Pw[w][l31][ks2 * 16 + h5 * 8];
            const short4v plo = *(const short4v*)pp;
            const short4v phi = *(const short4v*)(pp + 4);
            const short8 pfr = __builtin_shufflevector(plo, phi, 0, 1, 2, 3, 4, 5, 6, 7);
#pragma unroll
            for (int nt = 0; nt < 4; ++nt) {
                const short* vp = &Vt[nt * 32 + l31][ks2 * 16 + h5 * 8];
                const short4v vlo = *(const short4v*)vp;
                const short4v vhi = *(const short4v*)(vp + 4);
                const short8 vf = __builtin_shufflevector(vlo, vhi, 0, 1, 2, 3, 4, 5, 6, 7);
                oacc[nt] = __builtin_amdgcn_mfma_f32_32x32x16_bf16(pfr, vf, oacc[nt], 0, 0, 0);
            }
        }
    }

    // epilogue: store UNNORMALIZED O-partial (bf16) + l-partial (f32)
#pragma unroll
    for (int r = 0; r < 16; ++r) {
        const int row  = (r & 3) + 8 * (r >> 2) + 4 * h5;
        const int t    = t0 + w * 32 + row;
        const int grow = t * B_SZ + b;
        short* op = Opart + ((size_t)split * TB + grow) * D_DIM + h * HD;
#pragma unroll
        for (int nt = 0; nt < 3; ++nt)
            op[nt * 32 + l31] = f2bf(oacc[nt][r]);
        if (l31 == 0)
            lpart[((size_t)split * TB + grow) * H_NUM + h] = oacc[3][r];
    }
}

// ---------------------------------------------------------------------------
// Combine: ctx = (sum_c Opart[c]) / (sum_c lpart[c]).  One block per row,
// 192 active lanes x 4 d each, short4 vector loads.
// ---------------------------------------------------------------------------
__global__ __launch_bounds__(256)
void attn_combine(const short* __restrict__ Opart, const float* __restrict__ lpart,
                  short* __restrict__ ctx) {
    const int row = blockIdx.x;
    const int tid = threadIdx.x;
    if (tid >= 192) return;
    const int d = tid * 4;
    const int h = d / 96;
    float o0 = 0.f, o1 = 0.f, o2 = 0.f, o3 = 0.f, l = 0.f;
#pragma unroll
    for (int c = 0; c < NSPLIT; ++c) {
        const short4v v = *(const short4v*)&Opart[((size_t)c * TB + row) * D_DIM + d];
        o0 += bf2f(v[0]); o1 += bf2f(v[1]); o2 += bf2f(v[2]); o3 += bf2f(v[3]);
        l += lpart[((size_t)c * TB + row) * H_NUM + h];
    }
    const float iv = 1.f / l;
    short4v r;
    r[0] = f2bf(o0 * iv); r[1] = f2bf(o1 * iv);
    r[2] = f2bf(o2 * iv); r[3] = f2bf(o3 * iv);
    *(short4v*)&ctx[(size_t)row * D_DIM + d] = r;
}

// ---------------------------------------------------------------------------
// Fused residual + LayerNorm: out = LN(xres + y)*g + b.  (unchanged)
// ---------------------------------------------------------------------------
template <typename XT, typename OT>
__global__ __launch_bounds__(256)
void ln_residual(const XT* __restrict__ xres, const short* __restrict__ y,
                 const float* __restrict__ g, const float* __restrict__ bb,
                 OT* __restrict__ out) {
    const int row = blockIdx.x;
    const int tid = threadIdx.x;
    const XT*    xr = xres + (size_t)row * D_DIM;
    const short* yr = y + (size_t)row * D_DIM;

    float vals[3];
    float s = 0.f, s2 = 0.f;
#pragma unroll
    for (int i = 0; i < 3; ++i) {
        const int d = tid + i * 256;
        float xv;
        if constexpr (sizeof(XT) == 2) xv = bf2f((short)xr[d]);
        else                           xv = (float)xr[d];
        const float t = xv + bf2f(yr[d]);
        vals[i] = t;
        s += t;
        s2 = fmaf(t, t, s2);
    }
#pragma unroll
    for (int off = 32; off > 0; off >>= 1) {
        s  += __shfl_down(s, off);
        s2 += __shfl_down(s2, off);
    }
    __shared__ float red_s[4], red_s2[4];
    const int wid = tid >> 6, lane = tid & 63;
    if (lane == 0) { red_s[wid] = s; red_s2[wid] = s2; }
    __syncthreads();
    __shared__ float sh_mean, sh_rstd;
    if (tid == 0) {
        const float ts  = red_s[0] + red_s[1] + red_s[2] + red_s[3];
        const float ts2 = red_s2[0] + red_s2[1] + red_s2[2] + red_s2[3];
        const float mean = ts * (1.f / D_DIM);
        const float var  = ts2 * (1.f / D_DIM) - mean * mean;
        sh_mean = mean;
        sh_rstd = rsqrtf(var + EPS);
    }
    __syncthreads();
    const float mean = sh_mean, rstd = sh_rstd;
#pragma unroll
    for (int i = 0; i < 3; ++i) {
        const int d = tid + i * 256;
        const float o = (vals[i] - mean) * rstd * g[d] + bb[d];
        if constexpr (sizeof(OT) == 2)
            out[(size_t)row * D_DIM + d] = (OT)f2bf(o);
        else
            out[(size_t)row * D_DIM + d] = o;
    }
}

// ---------------------------------------------------------------------------
// Launch
// ---------------------------------------------------------------------------
extern "C" void kernel_launch(void* const* d_in, const int* in_sizes, int n_in,
                              void* d_out, int out_size, void* d_ws, size_t ws_size,
                              hipStream_t stream) {
    const float* x     = (const float*)d_in[0];
    const float* wq    = (const float*)d_in[1];
    const float* bq    = (const float*)d_in[2];
    const float* wk    = (const float*)d_in[3];
    const float* bk    = (const float*)d_in[4];
    const float* wv    = (const float*)d_in[5];
    const float* bv    = (const float*)d_in[6];
    const float* wo    = (const float*)d_in[7];
    const float* bo    = (const float*)d_in[8];
    const float* ln1g  = (const float*)d_in[9];
    const float* ln1b  = (const float*)d_in[10];
    const float* w1    = (const float*)d_in[11];
    const float* b1    = (const float*)d_in[12];
    const float* w2    = (const float*)d_in[13];
    const float* b2    = (const float*)d_in[14];
    const float* ln2g  = (const float*)d_in[15];
    const float* ln2b  = (const float*)d_in[16];
    float* out = (float*)d_out;

    // workspace layout (bytes) — total 65,020,928 (< 75.5 MB proven in R1)
    char* ws = (char*)d_ws;
    short* qkvb  = (short*)(ws + 0);             // [TB,2304] bf16  0 .. 18,874,368
    short* ctxb  = (short*)(ws + 18874368);      // [TB,768]  bf16  .. 25,165,824
    short* hb    = (short*)(ws + 0);             // [TB,3072] bf16  (reuses qkvb+ctxb)
    short* xb    = (short*)(ws + 25165824);      // [TB,768]  bf16  .. 31,457,280
    short* Opart = (short*)(ws + 25165824);      // 4x[TB,768] bf16 .. 50,331,648 (over xb)
    float* lpart = (float*)(ws + 50331648);      // 4x[TB,8]  f32   .. 50,855,936
    short* tmpb  = (short*)(ws + 25165824);      // [TB,768]  bf16  (over dead Opart)
    short* x1b   = (short*)(ws + 31457280);      // [TB,768]  bf16  (over dead Opart)
    short* wqkv  = (short*)(ws + 50855936);      // [2304,768] bf16 .. 54,394,880
    short* wob   = (short*)(ws + 54394880);      // [768,768]  bf16 .. 55,574,528
    short* w1b   = (short*)(ws + 55574528);      // [3072,768] bf16 .. 60,293,120
    short* w2b   = (short*)(ws + 60293120);      // [768,3072] bf16 .. 65,011,712
    float* bqkv  = (float*)(ws + 65011712);      // [2304] f32      .. 65,020,928

    // fused fp32->bf16 conversions
    CvtArgs ca;
    ca.src[0] = x;  ca.dst[0] = xb;
    ca.src[1] = wq; ca.dst[1] = wqkv;
    ca.src[2] = wk; ca.dst[2] = wqkv + 768 * 768;
    ca.src[3] = wv; ca.dst[3] = wqkv + 2 * 768 * 768;
    ca.src[4] = wo; ca.dst[4] = wob;
    ca.src[5] = w1; ca.dst[5] = w1b;
    ca.src[6] = w2; ca.dst[6] = w2b;
    const int n4[7] = {TB * D_DIM / 4, 768 * 768 / 4, 768 * 768 / 4, 768 * 768 / 4,
                       768 * 768 / 4, FFN * 768 / 4, 768 * FFN / 4};
    int acc4 = 0;
    for (int i = 0; i < 7; ++i) { acc4 += n4[i]; ca.end4[i] = acc4; }
    cvt_all<<<(acc4 + 255) / 256, 256, 0, stream>>>(ca, acc4);
    concat_bias<<<(QKV_LD + 255) / 256, 256, 0, stream>>>(bq, bk, bv, bqkv);

    // fused QKV projection: [TB,2304] = xb @ wqkv^T + bqkv
    gemm_mfma<128, short, false><<<dim3(QKV_LD / 128, TB / 128), 256, 0, stream>>>(
        xb, wqkv, bqkv, qkvb, TB, QKV_LD, D_DIM);

    // attention (v4r: split-K x4, LDS P round-trip, exp2 softmax) + combine
    attn_mfma<<<dim3(T_LEN / 64, B_SZ * H_NUM, NSPLIT), dim3(128), 0, stream>>>(
        qkvb, Opart, lpart);
    attn_combine<<<dim3(TB), 256, 0, stream>>>(Opart, lpart, ctxb);

    // out projection (bf16 out) + LN1 (bf16 out)
    gemm_mfma<64, short, false><<<dim3(D_DIM / 64, TB / 128), 256, 0, stream>>>(
        ctxb, wob, bo, tmpb, TB, D_DIM, D_DIM);
    ln_residual<float, short><<<dim3(TB), 256, 0, stream>>>(x, tmpb, ln1g, ln1b, x1b);

    // FFN
    gemm_mfma<128, short, true><<<dim3(FFN / 128, TB / 128), 256, 0, stream>>>(
        x1b, w1b, b1, hb, TB, FFN, D_DIM);
    gemm_mfma<64, short, false><<<dim3(D_DIM / 64, TB / 128), 256, 0, stream>>>(
        hb, w2b, b2, tmpb, TB, D_DIM, FFN);
    ln_residual<short, float><<<dim3(TB), 256, 0, stream>>>(x1b, tmpb, ln2g, ln2b, out);
}

// Round 13
// 332.044 us; speedup vs baseline: 1.0176x; 1.0176x over previous
//
#include <hip/hip_runtime.h>
#include <hip/hip_bf16.h>
#include <math.h>

// Problem constants (fixed by the reference)
constexpr int T_LEN = 2048;
constexpr int B_SZ  = 2;
constexpr int D_DIM = 768;
constexpr int H_NUM = 8;
constexpr int HD    = 96;        // D/H
constexpr int FFN   = 3072;
constexpr float EPS = 1e-5f;
constexpr int TB    = T_LEN * B_SZ;   // 4096 rows
constexpr int QKV_LD = 3 * D_DIM;     // 2304
constexpr int NSPLIT = 4;             // attention split-K factor
constexpr int CHUNK  = T_LEN / NSPLIT;   // 512 keys per block
// (1/sqrt(96)) * log2(e): folded into wq/bq so softmax is a bare v_exp (2^x)
constexpr float SC_LOG2E = 0.14724444458547f;

typedef __attribute__((ext_vector_type(8)))  short short8;
typedef __attribute__((ext_vector_type(4)))  short short4v;
typedef __attribute__((ext_vector_type(4)))  float f32x4;
typedef __attribute__((ext_vector_type(16))) float f32x16;

__device__ __forceinline__ short f2bf(float f) {
    union { float f; unsigned u; } v; v.f = f;
    return (short)((v.u + 0x7FFFu + ((v.u >> 16) & 1u)) >> 16);   // RNE
}
__device__ __forceinline__ float bf2f(short s) {
    union { unsigned u; float f; } v;
    v.u = ((unsigned)(unsigned short)s) << 16;
    return v.f;
}
// packed f32x2 -> bf16x2 (V_CVT_PK_BF16_F32 on gfx950); a in low half
__device__ __forceinline__ unsigned pkbf(float a, float b) {
    union { __hip_bfloat162 h; unsigned u; } v;
    v.h = __float22bfloat162_rn(make_float2(a, b));
    return v.u;
}

// async global->LDS, 16B per lane; LDS dst = wave-uniform base + lane*16
__device__ __forceinline__ void async_ld16(const short* g, short* l) {
    __builtin_amdgcn_global_load_lds(
        (const __attribute__((address_space(1))) unsigned int*)g,
        (__attribute__((address_space(3))) unsigned int*)l, 16, 0, 0);
}

// ---------------------------------------------------------------------------
// Prep: fused fp32 -> bf16 conversion over 7 segments (x + 6 weight blobs),
// with a per-segment scale (wq is pre-scaled by SC_LOG2E so attention's
// softmax exp becomes a bare v_exp_f32).
// ---------------------------------------------------------------------------
struct CvtArgs {
    const float* src[7];
    short*       dst[7];
    float        scl[7];
    int          end4[7];   // cumulative segment ends, in float4 units
};

__global__ __launch_bounds__(256)
void cvt_all(CvtArgs a, int total4) {
    const int i = blockIdx.x * 256 + threadIdx.x;
    if (i >= total4) return;
    int s = 0;
    while (i >= a.end4[s]) ++s;
    const int base = s ? a.end4[s - 1] : 0;
    const int j = i - base;
    const float sc = a.scl[s];
    const float4 v = ((const float4*)a.src[s])[j];
    short4v o;
    o[0] = f2bf(v.x * sc); o[1] = f2bf(v.y * sc);
    o[2] = f2bf(v.z * sc); o[3] = f2bf(v.w * sc);
    *(short4v*)(a.dst[s] + (size_t)j * 4) = o;
}

__global__ __launch_bounds__(256)
void concat_bias(const float* __restrict__ bq, const float* __restrict__ bk,
                 const float* __restrict__ bv, float* __restrict__ dst) {
    const int i = blockIdx.x * 256 + threadIdx.x;
    if (i >= QKV_LD) return;
    dst[i] = (i < 768) ? bq[i] * SC_LOG2E : (i < 1536 ? bk[i - 768] : bv[i - 1536]);
}

// ---------------------------------------------------------------------------
// bf16 MFMA GEMM: C[M,N] = A[M,K] @ W[N,K]^T + bias[N]  (optional ReLU)
// m97-style: 128(M) x BN tile, BK=32, 256 threads = 4 waves (unchanged).
// ---------------------------------------------------------------------------
template <int BN, typename OutT, bool RELU>
__global__ __launch_bounds__(256)
void gemm_mfma(const short* __restrict__ A, const short* __restrict__ W,
               const float* __restrict__ bias, OutT* __restrict__ C,
               int M, int N, int K) {
    constexpr int NI = BN / 32;   // 16-col tiles per wave
    __shared__ __align__(16) short As[128 * 32];
    __shared__ __align__(16) short Bs[BN * 32];

    const int tid  = threadIdx.x;
    const int w    = tid >> 6;
    const int lane = tid & 63;
    const int l16  = lane & 15;
    const int q4   = lane >> 4;          // 0..3
    const int row0 = blockIdx.y * 128;
    const int col0 = blockIdx.x * BN;
    const int wm   = (w >> 1) * 64;      // wave m-offset in tile
    const int wn   = (w & 1) * (BN / 2); // wave n-offset in tile

    const short* gA0 = A + (size_t)(row0 + (tid >> 2)) * K + (tid & 3) * 8;
    const short* gA1 = gA0 + (size_t)64 * K;
    const short* gB0 = W + (size_t)(col0 + (tid >> 2)) * K + (tid & 3) * 8;
    const short* gB1 = gB0 + (size_t)64 * K;
    short* ldsA0 = As + w * 512;           // wave-uniform bases
    short* ldsA1 = As + 2048 + w * 512;
    short* ldsB0 = Bs + w * 512;
    short* ldsB1 = Bs + 2048 + w * 512;   // only used when BN==128

    f32x4 acc[4][NI];
#pragma unroll
    for (int mi = 0; mi < 4; ++mi)
#pragma unroll
        for (int ni = 0; ni < NI; ++ni)
#pragma unroll
            for (int r = 0; r < 4; ++r) acc[mi][ni][r] = 0.f;

    for (int k0 = 0; k0 < K; k0 += 32) {
        async_ld16(gA0, ldsA0);
        async_ld16(gA1, ldsA1);
        async_ld16(gB0, ldsB0);
        if constexpr (BN == 128) async_ld16(gB1, ldsB1);
        gA0 += 32; gA1 += 32; gB0 += 32;
        if constexpr (BN == 128) gB1 += 32;
        __syncthreads();   // drain glds

        short8 af[4], bfr[NI];
#pragma unroll
        for (int mi = 0; mi < 4; ++mi)
            af[mi] = *(const short8*)&As[(wm + mi * 16 + l16) * 32 + q4 * 8];
#pragma unroll
        for (int ni = 0; ni < NI; ++ni)
            bfr[ni] = *(const short8*)&Bs[(wn + ni * 16 + l16) * 32 + q4 * 8];
#pragma unroll
        for (int mi = 0; mi < 4; ++mi)
#pragma unroll
            for (int ni = 0; ni < NI; ++ni)
                acc[mi][ni] = __builtin_amdgcn_mfma_f32_16x16x32_bf16(
                    af[mi], bfr[ni], acc[mi][ni], 0, 0, 0);
        __syncthreads();
    }

    float bcol[NI];
#pragma unroll
    for (int ni = 0; ni < NI; ++ni) bcol[ni] = bias[col0 + wn + ni * 16 + l16];
#pragma unroll
    for (int mi = 0; mi < 4; ++mi) {
#pragma unroll
        for (int r = 0; r < 4; ++r) {
            const int row = row0 + wm + mi * 16 + q4 * 4 + r;
#pragma unroll
            for (int ni = 0; ni < NI; ++ni) {
                float v = acc[mi][ni][r] + bcol[ni];
                if (RELU) v = fmaxf(v, 0.f);
                const int col = col0 + wn + ni * 16 + l16;
                if constexpr (sizeof(OutT) == 2)
                    C[(size_t)row * N + col] = (OutT)f2bf(v);
                else
                    C[(size_t)row * N + col] = v;
            }
        }
    }
}

// ---------------------------------------------------------------------------
// MFMA bf16 flash attention v4s: split-K + no-max softmax.
// Q is pre-scaled by scale*log2e in the QKV projection, so P = 2^S via a
// single v_exp_f32 (no mul, no libm). P bf16 conversion uses packed
// v_cvt_pk_bf16_f32 (8 pk + 8 shr vs 64 manual-RNE insts). LDS P round-trip
// retained (r11: independent b16 writes overlap better than shuffle chains).
// Grid (T/64, B*H, NSPLIT) = 2048 blocks; 64 q-rows x 512 keys per block;
// writes UNNORMALIZED partial O (bf16) + partial denominator l (f32).
// ---------------------------------------------------------------------------
__global__ __launch_bounds__(128)
void attn_mfma(const short* __restrict__ qkv, short* __restrict__ Opart,
               float* __restrict__ lpart) {
    __shared__ short Ks[32][112];    // [key][d] bf16, padded
    __shared__ short Vt[128][44];    // [d][key] bf16, stride 44 (2-way banks)
    __shared__ short Pw[2][32][36];  // per-wave P, stride 36

    const int tid  = threadIdx.x;
    const int w    = tid >> 6;
    const int lane = tid & 63;
    const int l31  = lane & 31;
    const int h5   = lane >> 5;
    const int t0   = blockIdx.x * 64;
    const int bh   = blockIdx.y;
    const int split = blockIdx.z;
    const int b    = bh >> 3;
    const int h    = bh & 7;

    // Vt rows 96..127: row 96 = ones (denominator column), rest zero
    for (int i = tid; i < 32 * 44; i += 128) {
        const int rr = i / 44, cc = i % 44;
        Vt[96 + rr][cc] = (rr == 0 && cc < 32) ? (short)0x3F80 : (short)0;
    }

    // Q fragments straight from global bf16 (wave-private 32 q-rows)
    short8 qf[6];
    {
        const int qrow = t0 + w * 32 + l31;
        const short* qb = qkv + ((size_t)qrow * B_SZ + b) * QKV_LD + h * HD;
#pragma unroll
        for (int ks = 0; ks < 6; ++ks)
            qf[ks] = *(const short8*)&qb[ks * 16 + h5 * 8];
    }

    // --- staging assignments (wave-specialized), chunk-local keys ---
    const int k_row = lane >> 1;                  // wave 0: key row
    const int k_off = (lane & 1) * 48;            // wave 0: d-half
    const short* gK = qkv + ((size_t)(split * CHUNK + k_row) * B_SZ + b) * QKV_LD
                      + D_DIM + h * HD + k_off;
    const int dg = (lane & 7) * 12;               // wave 1: d-group
    const int kg = (lane >> 3) * 4;               // wave 1: key-group
    const short* gV = qkv + ((size_t)(split * CHUNK + kg) * B_SZ + b) * QKV_LD
                      + 2 * D_DIM + h * HD + dg;
    const size_t step  = (size_t)32 * B_SZ * QKV_LD;
    const size_t vrow  = (size_t)B_SZ * QKV_LD;   // one key row

    f32x16 oacc[4];
#pragma unroll
    for (int nt = 0; nt < 4; ++nt)
#pragma unroll
        for (int r = 0; r < 16; ++r) oacc[nt][r] = 0.f;

    // prefetch tile 0 (wave-specialized, registers)
    short8  kpf[6];
    short4v vpf[4][3];
    if (w == 0) {
#pragma unroll
        for (int j = 0; j < 6; ++j) kpf[j] = *(const short8*)(gK + j * 8);
    } else {
#pragma unroll
        for (int r = 0; r < 4; ++r)
#pragma unroll
            for (int c = 0; c < 3; ++c)
                vpf[r][c] = *(const short4v*)(gV + r * vrow + c * 4);
    }

    for (int it = 0; it < CHUNK / 32; ++it) {
        __syncthreads();   // previous tile fully consumed by both waves
        if (w == 0) {
#pragma unroll
            for (int j = 0; j < 6; ++j)
                *(short8*)&Ks[k_row][k_off + j * 8] = kpf[j];
        } else {
#pragma unroll
            for (int d = 0; d < 12; ++d) {
                short4v t;
                t[0] = vpf[0][d >> 2][d & 3];
                t[1] = vpf[1][d >> 2][d & 3];
                t[2] = vpf[2][d >> 2][d & 3];
                t[3] = vpf[3][d >> 2][d & 3];
                *(short4v*)&Vt[dg + d][kg] = t;
            }
        }
        __syncthreads();

        // prefetch next tile (latency hides behind this tile's compute)
        if (it + 1 < CHUNK / 32) {
            const size_t off = (size_t)(it + 1) * step;
            if (w == 0) {
#pragma unroll
                for (int j = 0; j < 6; ++j)
                    kpf[j] = *(const short8*)(gK + off + j * 8);
            } else {
#pragma unroll
                for (int r = 0; r < 4; ++r)
#pragma unroll
                    for (int c = 0; c < 3; ++c)
                        vpf[r][c] = *(const short4v*)(gV + off + r * vrow + c * 4);
            }
        }

        // S = Q.K^T  (Q pre-scaled by scale*log2e)
        f32x16 sa;
#pragma unroll
        for (int r = 0; r < 16; ++r) sa[r] = 0.f;
#pragma unroll
        for (int ks = 0; ks < 6; ++ks) {
            const short8 kf = *(const short8*)&Ks[l31][ks * 16 + h5 * 8];
            sa = __builtin_amdgcn_mfma_f32_32x32x16_bf16(qf[ks], kf, sa, 0, 0, 0);
        }

        // P = 2^S (bare v_exp); packed cvt to bf16; C-layout -> LDS -> A-layout
        float pvx[16];
#pragma unroll
        for (int r = 0; r < 16; ++r) pvx[r] = __builtin_amdgcn_exp2f(sa[r]);
#pragma unroll
        for (int rp = 0; rp < 8; ++rp) {
            const unsigned u = pkbf(pvx[2 * rp], pvx[2 * rp + 1]);
            const int row = ((2 * rp) & 3) + 8 * ((2 * rp) >> 2) + 4 * h5;
            Pw[w][row][l31]     = (short)(u & 0xFFFFu);
            Pw[w][row + 1][l31] = (short)(u >> 16);
        }

        // O += P.V  (+ denominator column in n-tile 3)
#pragma unroll
        for (int ks2 = 0; ks2 < 2; ++ks2) {
            const short* pp = &Pw[w][l31][ks2 * 16 + h5 * 8];
            const short4v plo = *(const short4v*)pp;
            const short4v phi = *(const short4v*)(pp + 4);
            const short8 pfr = __builtin_shufflevector(plo, phi, 0, 1, 2, 3, 4, 5, 6, 7);
#pragma unroll
            for (int nt = 0; nt < 4; ++nt) {
                const short* vp = &Vt[nt * 32 + l31][ks2 * 16 + h5 * 8];
                const short4v vlo = *(const short4v*)vp;
                const short4v vhi = *(const short4v*)(vp + 4);
                const short8 vf = __builtin_shufflevector(vlo, vhi, 0, 1, 2, 3, 4, 5, 6, 7);
                oacc[nt] = __builtin_amdgcn_mfma_f32_32x32x16_bf16(pfr, vf, oacc[nt], 0, 0, 0);
            }
        }
    }

    // epilogue: store UNNORMALIZED O-partial (bf16) + l-partial (f32)
#pragma unroll
    for (int r = 0; r < 16; ++r) {
        const int row  = (r & 3) + 8 * (r >> 2) + 4 * h5;
        const int t    = t0 + w * 32 + row;
        const int grow = t * B_SZ + b;
        short* op = Opart + ((size_t)split * TB + grow) * D_DIM + h * HD;
#pragma unroll
        for (int nt = 0; nt < 3; ++nt)
            op[nt * 32 + l31] = f2bf(oacc[nt][r]);
        if (l31 == 0)
            lpart[((size_t)split * TB + grow) * H_NUM + h] = oacc[3][r];
    }
}

// ---------------------------------------------------------------------------
// Combine: ctx = (sum_c Opart[c]) / (sum_c lpart[c]).  One block per row,
// 192 active lanes x 4 d each, short4 vector loads.
// ---------------------------------------------------------------------------
__global__ __launch_bounds__(256)
void attn_combine(const short* __restrict__ Opart, const float* __restrict__ lpart,
                  short* __restrict__ ctx) {
    const int row = blockIdx.x;
    const int tid = threadIdx.x;
    if (tid >= 192) return;
    const int d = tid * 4;
    const int h = d / 96;
    float o0 = 0.f, o1 = 0.f, o2 = 0.f, o3 = 0.f, l = 0.f;
#pragma unroll
    for (int c = 0; c < NSPLIT; ++c) {
        const short4v v = *(const short4v*)&Opart[((size_t)c * TB + row) * D_DIM + d];
        o0 += bf2f(v[0]); o1 += bf2f(v[1]); o2 += bf2f(v[2]); o3 += bf2f(v[3]);
        l += lpart[((size_t)c * TB + row) * H_NUM + h];
    }
    const float iv = 1.f / l;
    short4v r;
    r[0] = f2bf(o0 * iv); r[1] = f2bf(o1 * iv);
    r[2] = f2bf(o2 * iv); r[3] = f2bf(o3 * iv);
    *(short4v*)&ctx[(size_t)row * D_DIM + d] = r;
}

// ---------------------------------------------------------------------------
// Fused residual + LayerNorm: out = LN(xres + y)*g + b.  (unchanged)
// ---------------------------------------------------------------------------
template <typename XT, typename OT>
__global__ __launch_bounds__(256)
void ln_residual(const XT* __restrict__ xres, const short* __restrict__ y,
                 const float* __restrict__ g, const float* __restrict__ bb,
                 OT* __restrict__ out) {
    const int row = blockIdx.x;
    const int tid = threadIdx.x;
    const XT*    xr = xres + (size_t)row * D_DIM;
    const short* yr = y + (size_t)row * D_DIM;

    float vals[3];
    float s = 0.f, s2 = 0.f;
#pragma unroll
    for (int i = 0; i < 3; ++i) {
        const int d = tid + i * 256;
        float xv;
        if constexpr (sizeof(XT) == 2) xv = bf2f((short)xr[d]);
        else                           xv = (float)xr[d];
        const float t = xv + bf2f(yr[d]);
        vals[i] = t;
        s += t;
        s2 = fmaf(t, t, s2);
    }
#pragma unroll
    for (int off = 32; off > 0; off >>= 1) {
        s  += __shfl_down(s, off);
        s2 += __shfl_down(s2, off);
    }
    __shared__ float red_s[4], red_s2[4];
    const int wid = tid >> 6, lane = tid & 63;
    if (lane == 0) { red_s[wid] = s; red_s2[wid] = s2; }
    __syncthreads();
    __shared__ float sh_mean, sh_rstd;
    if (tid == 0) {
        const float ts  = red_s[0] + red_s[1] + red_s[2] + red_s[3];
        const float ts2 = red_s2[0] + red_s2[1] + red_s2[2] + red_s2[3];
        const float mean = ts * (1.f / D_DIM);
        const float var  = ts2 * (1.f / D_DIM) - mean * mean;
        sh_mean = mean;
        sh_rstd = rsqrtf(var + EPS);
    }
    __syncthreads();
    const float mean = sh_mean, rstd = sh_rstd;
#pragma unroll
    for (int i = 0; i < 3; ++i) {
        const int d = tid + i * 256;
        const float o = (vals[i] - mean) * rstd * g[d] + bb[d];
        if constexpr (sizeof(OT) == 2)
            out[(size_t)row * D_DIM + d] = (OT)f2bf(o);
        else
            out[(size_t)row * D_DIM + d] = o;
    }
}

// ---------------------------------------------------------------------------
// Launch
// ---------------------------------------------------------------------------
extern "C" void kernel_launch(void* const* d_in, const int* in_sizes, int n_in,
                              void* d_out, int out_size, void* d_ws, size_t ws_size,
                              hipStream_t stream) {
    const float* x     = (const float*)d_in[0];
    const float* wq    = (const float*)d_in[1];
    const float* bq    = (const float*)d_in[2];
    const float* wk    = (const float*)d_in[3];
    const float* bk    = (const float*)d_in[4];
    const float* wv    = (const float*)d_in[5];
    const float* bv    = (const float*)d_in[6];
    const float* wo    = (const float*)d_in[7];
    const float* bo    = (const float*)d_in[8];
    const float* ln1g  = (const float*)d_in[9];
    const float* ln1b  = (const float*)d_in[10];
    const float* w1    = (const float*)d_in[11];
    const float* b1    = (const float*)d_in[12];
    const float* w2    = (const float*)d_in[13];
    const float* b2    = (const float*)d_in[14];
    const float* ln2g  = (const float*)d_in[15];
    const float* ln2b  = (const float*)d_in[16];
    float* out = (float*)d_out;

    // workspace layout (bytes) — total 65,020,928 (< 75.5 MB proven in R1)
    char* ws = (char*)d_ws;
    short* qkvb  = (short*)(ws + 0);             // [TB,2304] bf16  0 .. 18,874,368
    short* ctxb  = (short*)(ws + 18874368);      // [TB,768]  bf16  .. 25,165,824
    short* hb    = (short*)(ws + 0);             // [TB,3072] bf16  (reuses qkvb+ctxb)
    short* xb    = (short*)(ws + 25165824);      // [TB,768]  bf16  .. 31,457,280
    short* Opart = (short*)(ws + 25165824);      // 4x[TB,768] bf16 .. 50,331,648 (over xb)
    float* lpart = (float*)(ws + 50331648);      // 4x[TB,8]  f32   .. 50,855,936
    short* tmpb  = (short*)(ws + 25165824);      // [TB,768]  bf16  (over dead Opart)
    short* x1b   = (short*)(ws + 31457280);      // [TB,768]  bf16  (over dead Opart)
    short* wqkv  = (short*)(ws + 50855936);      // [2304,768] bf16 .. 54,394,880
    short* wob   = (short*)(ws + 54394880);      // [768,768]  bf16 .. 55,574,528
    short* w1b   = (short*)(ws + 55574528);      // [3072,768] bf16 .. 60,293,120
    short* w2b   = (short*)(ws + 60293120);      // [768,3072] bf16 .. 65,011,712
    float* bqkv  = (float*)(ws + 65011712);      // [2304] f32      .. 65,020,928

    // fused fp32->bf16 conversions (wq pre-scaled by scale*log2e)
    CvtArgs ca;
    ca.src[0] = x;  ca.dst[0] = xb;   ca.scl[0] = 1.f;
    ca.src[1] = wq; ca.dst[1] = wqkv; ca.scl[1] = SC_LOG2E;
    ca.src[2] = wk; ca.dst[2] = wqkv + 768 * 768;     ca.scl[2] = 1.f;
    ca.src[3] = wv; ca.dst[3] = wqkv + 2 * 768 * 768; ca.scl[3] = 1.f;
    ca.src[4] = wo; ca.dst[4] = wob;  ca.scl[4] = 1.f;
    ca.src[5] = w1; ca.dst[5] = w1b;  ca.scl[5] = 1.f;
    ca.src[6] = w2; ca.dst[6] = w2b;  ca.scl[6] = 1.f;
    const int n4[7] = {TB * D_DIM / 4, 768 * 768 / 4, 768 * 768 / 4, 768 * 768 / 4,
                       768 * 768 / 4, FFN * 768 / 4, 768 * FFN / 4};
    int acc4 = 0;
    for (int i = 0; i < 7; ++i) { acc4 += n4[i]; ca.end4[i] = acc4; }
    cvt_all<<<(acc4 + 255) / 256, 256, 0, stream>>>(ca, acc4);
    concat_bias<<<(QKV_LD + 255) / 256, 256, 0, stream>>>(bq, bk, bv, bqkv);

    // fused QKV projection: [TB,2304] = xb @ wqkv^T + bqkv
    gemm_mfma<128, short, false><<<dim3(QKV_LD / 128, TB / 128), 256, 0, stream>>>(
        xb, wqkv, bqkv, qkvb, TB, QKV_LD, D_DIM);

    // attention (v4s: split-K x4, bare-v_exp softmax, packed P cvt) + combine
    attn_mfma<<<dim3(T_LEN / 64, B_SZ * H_NUM, NSPLIT), dim3(128), 0, stream>>>(
        qkvb, Opart, lpart);
    attn_combine<<<dim3(TB), 256, 0, stream>>>(Opart, lpart, ctxb);

    // out projection (bf16 out) + LN1 (bf16 out)
    gemm_mfma<64, short, false><<<dim3(D_DIM / 64, TB / 128), 256, 0, stream>>>(
        ctxb, wob, bo, tmpb, TB, D_DIM, D_DIM);
    ln_residual<float, short><<<dim3(TB), 256, 0, stream>>>(x, tmpb, ln1g, ln1b, x1b);

    // FFN
    gemm_mfma<128, short, true><<<dim3(FFN / 128, TB / 128), 256, 0, stream>>>(
        x1b, w1b, b1, hb, TB, FFN, D_DIM);
    gemm_mfma<64, short, false><<<dim3(D_DIM / 64, TB / 128), 256, 0, stream>>>(
        hb, w2b, b2, tmpb, TB, D_DIM, FFN);
    ln_residual<short, float><<<dim3(TB), 256, 0, stream>>>(x1b, tmpb, ln2g, ln2b, out);
}